// Round 2
// baseline (499.740 us; speedup 1.0000x reference)
//
#include <hip/hip_runtime.h>

#define NN 10000
#define BB 8
#define EE 160000
#define DH 128
#define DC 256
#define LN_EPS 1e-5f

typedef unsigned short ushort_t;
typedef unsigned int uint_t;

typedef __bf16 bf16x8 __attribute__((ext_vector_type(8)));
typedef float floatx4 __attribute__((ext_vector_type(4)));

__device__ __forceinline__ float b2f(uint_t u) { return __uint_as_float(u << 16); }
__device__ __forceinline__ ushort_t f2b(float f) {
    uint_t u = __float_as_uint(f);
    return (ushort_t)((u + 0x7fffu + ((u >> 16) & 1u)) >> 16);
}
__device__ __forceinline__ uint_t pack2(float lo, float hi) {
    return (uint_t)f2b(lo) | ((uint_t)f2b(hi) << 16);
}
__device__ __forceinline__ float sigm(float x) { return 1.0f / (1.0f + __expf(-x)); }

// ---------------- CSR build ----------------

__global__ void count_deg(const int* __restrict__ ei, int* __restrict__ cnt) {
    int e = blockIdx.x * 256 + threadIdx.x;
    if (e < EE) atomicAdd(&cnt[ei[EE + e]], 1);
}

__global__ void compute_dis(const int* __restrict__ cnt, float* __restrict__ dis) {
    int n = blockIdx.x * 256 + threadIdx.x;
    if (n < NN) dis[n] = rsqrtf((float)(cnt[n] + 1));
}

__global__ __launch_bounds__(1024) void scan_k(const int* __restrict__ cnt,
                                               int* __restrict__ offs,
                                               int* __restrict__ cursor) {
    __shared__ int s[1024];
    const int t = threadIdx.x;
    int carry = 0;
    for (int base = 0; base < NN; base += 1024) {
        int idx = base + t;
        int x = (idx < NN) ? cnt[idx] : 0;
        s[t] = x;
        __syncthreads();
        for (int off = 1; off < 1024; off <<= 1) {
            int v = s[t];
            int u = (t >= off) ? s[t - off] : 0;
            __syncthreads();
            s[t] = v + u;
            __syncthreads();
        }
        int incl = s[t];
        if (idx < NN) {
            int excl = carry + incl - x;
            offs[idx] = excl;
            cursor[idx] = excl;
        }
        int tot = s[1023];
        __syncthreads();
        carry += tot;
    }
    if (t == 0) offs[NN] = carry;
}

__global__ void fill_csr(const int* __restrict__ ei, int* __restrict__ cursor,
                         const float* __restrict__ dis, int* __restrict__ csr_src,
                         float* __restrict__ csr_norm) {
    int e = blockIdx.x * 256 + threadIdx.x;
    if (e < EE) {
        int s = ei[e];
        int d = ei[EE + e];
        int pos = atomicAdd(&cursor[d], 1);
        csr_src[pos] = s;
        csr_norm[pos] = dis[s] * dis[d];
    }
}

// ---------------- GEMM: T = [X | H] @ [Wa|Wb] (f32 in via bf16 convert, bf16 out, fp32 acc)
// 64x64 tile per block, K=256 in two stages of 128. RBF16: right half of A is bf16.

template <int RBF16>
__global__ __launch_bounds__(256) void gemm_k(const float* __restrict__ X,
                                              const void* __restrict__ Hv,
                                              const float* __restrict__ Wa,
                                              const float* __restrict__ Wb,
                                              ushort_t* __restrict__ T, int ldt) {
    __shared__ __align__(16) ushort_t As[64 * 136];
    __shared__ __align__(16) ushort_t Bs[64 * 136];
    const int tid = threadIdx.x;
    const int row0 = blockIdx.x * 64;
    const int cg0 = blockIdx.y * 64;
    const float* W = (cg0 < 128) ? (Wa + cg0) : (Wb + (cg0 - 128));

    const int wave = tid >> 6, lane = tid & 63;
    const int mBase = (wave >> 1) * 32, cBase = (wave & 1) * 32;
    const int l15 = lane & 15, q = lane >> 4;

    floatx4 acc00 = {0.f, 0.f, 0.f, 0.f};
    floatx4 acc01 = acc00, acc10 = acc00, acc11 = acc00;

    for (int st = 0; st < 2; ++st) {
        {  // stage A tile: 64 rows x 128 k (global k = st*128 + local k)
            const int ar = tid >> 2;
            const int ak0 = (tid & 3) * 32;
            if (st == 0 || !RBF16) {
                const float* src =
                    (st == 0) ? (X + (size_t)(row0 + ar) * DH + ak0)
                              : ((const float*)Hv + (size_t)(row0 + ar) * DH + ak0);
#pragma unroll
                for (int i = 0; i < 4; ++i) {
                    float4 f0 = *(const float4*)(src + i * 8);
                    float4 f1 = *(const float4*)(src + i * 8 + 4);
                    ushort_t tmp[8] __attribute__((aligned(16)));
                    tmp[0] = f2b(f0.x); tmp[1] = f2b(f0.y);
                    tmp[2] = f2b(f0.z); tmp[3] = f2b(f0.w);
                    tmp[4] = f2b(f1.x); tmp[5] = f2b(f1.y);
                    tmp[6] = f2b(f1.z); tmp[7] = f2b(f1.w);
                    *(uint4*)&As[ar * 136 + ak0 + i * 8] = *(const uint4*)tmp;
                }
            } else {
                const ushort_t* src = (const ushort_t*)Hv + (size_t)(row0 + ar) * DH + ak0;
#pragma unroll
                for (int i = 0; i < 4; ++i)
                    *(uint4*)&As[ar * 136 + ak0 + i * 8] = *(const uint4*)(src + i * 8);
            }
        }
        {  // stage B tile transposed: Bs[col][k]
            const int bc = tid & 63;
            const int bk0 = (tid >> 6) * 32;
#pragma unroll
            for (int i = 0; i < 4; ++i) {
                ushort_t tmp[8] __attribute__((aligned(16)));
#pragma unroll
                for (int j = 0; j < 8; ++j)
                    tmp[j] = f2b(W[(size_t)(st * 128 + bk0 + i * 8 + j) * 128 + bc]);
                *(uint4*)&Bs[bc * 136 + bk0 + i * 8] = *(const uint4*)tmp;
            }
        }
        __syncthreads();
#pragma unroll
        for (int k0 = 0; k0 < 4; ++k0) {
            const int ko = k0 * 32 + q * 8;
            bf16x8 a0 = *(const bf16x8*)&As[(mBase + l15) * 136 + ko];
            bf16x8 a1 = *(const bf16x8*)&As[(mBase + 16 + l15) * 136 + ko];
            bf16x8 b0 = *(const bf16x8*)&Bs[(cBase + l15) * 136 + ko];
            bf16x8 b1 = *(const bf16x8*)&Bs[(cBase + 16 + l15) * 136 + ko];
            acc00 = __builtin_amdgcn_mfma_f32_16x16x32_bf16(a0, b0, acc00, 0, 0, 0);
            acc01 = __builtin_amdgcn_mfma_f32_16x16x32_bf16(a0, b1, acc01, 0, 0, 0);
            acc10 = __builtin_amdgcn_mfma_f32_16x16x32_bf16(a1, b0, acc10, 0, 0, 0);
            acc11 = __builtin_amdgcn_mfma_f32_16x16x32_bf16(a1, b1, acc11, 0, 0, 0);
        }
        __syncthreads();
    }

    // C/D layout: col = lane&15, row = (lane>>4)*4 + reg
#pragma unroll
    for (int i = 0; i < 2; ++i) {
        floatx4 aj0 = i ? acc10 : acc00;
        floatx4 aj1 = i ? acc11 : acc01;
#pragma unroll
        for (int v = 0; v < 4; ++v) {
            int row = row0 + mBase + i * 16 + q * 4 + v;
            T[(size_t)row * ldt + cg0 + cBase + l15] = f2b(aj0[v]);
            T[(size_t)row * ldt + cg0 + cBase + 16 + l15] = f2b(aj1[v]);
        }
    }
}

// ---------------- Gather 1: agg of t_zr (256-wide), epilogue -> z, r*h ----------------
// One wave per (batch,node). batch = blockIdx&7 for XCD/L2 locality.

__global__ __launch_bounds__(256) void gather_zr(
    const ushort_t* __restrict__ t_zr, const float* __restrict__ h_prev,
    const int* __restrict__ offs, const int* __restrict__ csr_src,
    const float* __restrict__ csr_norm, const float* __restrict__ dis,
    const float* __restrict__ bz, const float* __restrict__ br,
    ushort_t* __restrict__ z_buf, ushort_t* __restrict__ rh_buf) {
    const int tid = threadIdx.x, wave = tid >> 6, lane = tid & 63;
    const int b = blockIdx.x & 7;
    const int n = (blockIdx.x >> 3) * 4 + wave;
    const size_t nb = (size_t)b * NN + n;
    const int c = lane * 4;

    float w0 = dis[n];
    w0 *= w0;  // self-loop weight = 1/deg
    uint2 v0 = *(const uint2*)(t_zr + nb * DC + c);
    float a0 = w0 * b2f(v0.x & 0xffffu), a1 = w0 * b2f(v0.x >> 16);
    float a2 = w0 * b2f(v0.y & 0xffffu), a3 = w0 * b2f(v0.y >> 16);

    const int e1 = offs[n + 1];
    for (int e = offs[n]; e < e1; ++e) {
        int s = csr_src[e];
        float w = csr_norm[e];
        uint2 v = *(const uint2*)(t_zr + ((size_t)b * NN + s) * DC + c);
        a0 += w * b2f(v.x & 0xffffu);
        a1 += w * b2f(v.x >> 16);
        a2 += w * b2f(v.y & 0xffffu);
        a3 += w * b2f(v.y >> 16);
    }

    if (lane < 32) {  // z half: c in [0,128)
        const int zc = c;
        float z0 = sigm(a0 + bz[zc + 0]);
        float z1 = sigm(a1 + bz[zc + 1]);
        float z2 = sigm(a2 + bz[zc + 2]);
        float z3 = sigm(a3 + bz[zc + 3]);
        uint2 st;
        st.x = pack2(z0, z1);
        st.y = pack2(z2, z3);
        *(uint2*)(z_buf + nb * DH + zc) = st;
    } else {  // r half: compute r*h
        const int rc = c - DH;
        float r0 = sigm(a0 + br[rc + 0]);
        float r1 = sigm(a1 + br[rc + 1]);
        float r2 = sigm(a2 + br[rc + 2]);
        float r3 = sigm(a3 + br[rc + 3]);
        float4 hv = *(const float4*)(h_prev + nb * DH + rc);
        uint2 st;
        st.x = pack2(r0 * hv.x, r1 * hv.y);
        st.y = pack2(r2 * hv.z, r3 * hv.w);
        *(uint2*)(rh_buf + nb * DH + rc) = st;
    }
}

// ---------------- Gather 2: agg of t_c (128-wide) + GRU blend + LayerNorm ----------------

__global__ __launch_bounds__(256) void gather_c(
    const ushort_t* __restrict__ t_c, const float* __restrict__ h_prev,
    const int* __restrict__ offs, const int* __restrict__ csr_src,
    const float* __restrict__ csr_norm, const float* __restrict__ dis,
    const float* __restrict__ bcv, const ushort_t* __restrict__ z_buf,
    const float* __restrict__ gamma, const float* __restrict__ beta,
    float* __restrict__ out) {
    const int tid = threadIdx.x, wave = tid >> 6, lane = tid & 63;
    const int b = blockIdx.x & 7;
    const int n = (blockIdx.x >> 3) * 4 + wave;
    const size_t nb = (size_t)b * NN + n;
    const int c = lane * 2;

    float w0 = dis[n];
    w0 *= w0;
    uint_t v0 = *(const uint_t*)(t_c + nb * DH + c);
    float a0 = w0 * b2f(v0 & 0xffffu), a1 = w0 * b2f(v0 >> 16);

    const int e1 = offs[n + 1];
    for (int e = offs[n]; e < e1; ++e) {
        int s = csr_src[e];
        float w = csr_norm[e];
        uint_t v = *(const uint_t*)(t_c + ((size_t)b * NN + s) * DH + c);
        a0 += w * b2f(v & 0xffffu);
        a1 += w * b2f(v >> 16);
    }

    float hc0 = tanhf(a0 + bcv[c]);
    float hc1 = tanhf(a1 + bcv[c + 1]);
    uint_t zv = *(const uint_t*)(z_buf + nb * DH + c);
    float z0 = b2f(zv & 0xffffu), z1 = b2f(zv >> 16);
    float2 hv = *(const float2*)(h_prev + nb * DH + c);
    float hn0 = (1.0f - z0) * hv.x + z0 * hc0;
    float hn1 = (1.0f - z1) * hv.y + z1 * hc1;

    // LayerNorm over 128 (wave64 x 2 per lane)
    float s = hn0 + hn1;
#pragma unroll
    for (int o = 32; o > 0; o >>= 1) s += __shfl_xor(s, o);
    float mu = s * (1.0f / 128.0f);
    float d0 = hn0 - mu, d1 = hn1 - mu;
    float vv = d0 * d0 + d1 * d1;
#pragma unroll
    for (int o = 32; o > 0; o >>= 1) vv += __shfl_xor(vv, o);
    float inv = rsqrtf(vv * (1.0f / 128.0f) + LN_EPS);
    float2 ov;
    ov.x = d0 * inv * gamma[c] + beta[c];
    ov.y = d1 * inv * gamma[c + 1] + beta[c + 1];
    *(float2*)(out + nb * DH + c) = ov;
}

// ---------------- launch ----------------

extern "C" void kernel_launch(void* const* d_in, const int* in_sizes, int n_in,
                              void* d_out, int out_size, void* d_ws, size_t ws_size,
                              hipStream_t stream) {
    const float* x = (const float*)d_in[0];
    const int* ei = (const int*)d_in[1];
    const float* h = (const float*)d_in[2];
    const float* Wz = (const float*)d_in[3];
    const float* bz = (const float*)d_in[4];
    const float* Wr = (const float*)d_in[5];
    const float* br = (const float*)d_in[6];
    const float* Wc = (const float*)d_in[7];
    const float* bcv = (const float*)d_in[8];
    const float* gamma = (const float*)d_in[9];
    const float* beta = (const float*)d_in[10];
    float* out = (float*)d_out;

    char* w = (char*)d_ws;
    int* cnt = (int*)(w + 0);                // 40000 B
    int* offs = (int*)(w + 40960);           // 40004 B
    int* cursor = (int*)(w + 81920);         // 40000 B
    float* dis = (float*)(w + 122880);       // 40000 B
    int* csr_src = (int*)(w + 163840);       // 640000 B
    float* csr_norm = (float*)(w + 803840);  // 640000 B
    ushort_t* t_zr = (ushort_t*)(w + 1443840);    // 80000*256*2 = 40,960,000 B
    ushort_t* z_buf = (ushort_t*)(w + 42403840);  // 20,480,000 B
    ushort_t* rh_buf = (ushort_t*)(w + 62883840); // 20,480,000 B
    ushort_t* t_c = t_zr;  // t_zr dead after gather_zr; reuse for t_c

    hipMemsetAsync(cnt, 0, NN * sizeof(int), stream);
    count_deg<<<EE / 256, 256, 0, stream>>>(ei, cnt);
    compute_dis<<<(NN + 255) / 256, 256, 0, stream>>>(cnt, dis);
    scan_k<<<1, 1024, 0, stream>>>(cnt, offs, cursor);
    fill_csr<<<EE / 256, 256, 0, stream>>>(ei, cursor, dis, csr_src, csr_norm);

    // t_zr = [x|h] @ [Wz|Wr]  (80000x256)
    gemm_k<0><<<dim3(80000 / 64, 4), 256, 0, stream>>>(x, (const void*)h, Wz, Wr, t_zr, DC);
    gather_zr<<<(BB * NN) / 4, 256, 0, stream>>>(t_zr, h, offs, csr_src, csr_norm, dis,
                                                 bz, br, z_buf, rh_buf);
    // t_c = [x|r*h] @ Wc  (80000x128)
    gemm_k<1><<<dim3(80000 / 64, 2), 256, 0, stream>>>(x, (const void*)rh_buf, Wc, Wc, t_c, DH);
    gather_c<<<(BB * NN) / 4, 256, 0, stream>>>(t_c, h, offs, csr_src, csr_norm, dis,
                                                bcv, z_buf, gamma, beta, out);
}

// Round 3
// 381.369 us; speedup vs baseline: 1.3104x; 1.3104x over previous
//
#include <hip/hip_runtime.h>

#define NN 10000
#define BB 8
#define EE 160000
#define DH 128
#define LN_EPS 1e-5f

typedef unsigned short ushort_t;
typedef unsigned int uint_t;

typedef __bf16 bf16x8 __attribute__((ext_vector_type(8)));
typedef float floatx4 __attribute__((ext_vector_type(4)));

__device__ __forceinline__ float b2f(uint_t u) { return __uint_as_float(u << 16); }
__device__ __forceinline__ ushort_t f2b(float f) {
    uint_t u = __float_as_uint(f);
    return (ushort_t)((u + 0x7fffu + ((u >> 16) & 1u)) >> 16);
}
__device__ __forceinline__ uint_t pack2(float lo, float hi) {
    return (uint_t)f2b(lo) | ((uint_t)f2b(hi) << 16);
}
__device__ __forceinline__ float sigm(float x) { return 1.0f / (1.0f + __expf(-x)); }

// ---------------- CSR build ----------------

__global__ void count_deg(const int* __restrict__ ei, int* __restrict__ cnt) {
    int e = blockIdx.x * 256 + threadIdx.x;
    if (e < EE) atomicAdd(&cnt[ei[EE + e]], 1);
}

// 3-stage parallel scan (replaces single-block serial scan: 1 CU -> 40 blocks)
__global__ __launch_bounds__(256) void scan1(const int* __restrict__ cnt,
                                             int* __restrict__ offs,
                                             int* __restrict__ bsum) {
    __shared__ int s[256];
    const int t = threadIdx.x, idx = blockIdx.x * 256 + t;
    int x = (idx < NN) ? cnt[idx] : 0;
    s[t] = x;
    __syncthreads();
    for (int o = 1; o < 256; o <<= 1) {
        int v = s[t];
        int u = (t >= o) ? s[t - o] : 0;
        __syncthreads();
        s[t] = v + u;
        __syncthreads();
    }
    if (idx < NN) offs[idx] = s[t] - x;  // block-local exclusive
    if (t == 255) bsum[blockIdx.x] = s[255];
}

__global__ __launch_bounds__(64) void scan2(int* __restrict__ bsum, int* __restrict__ offs) {
    __shared__ int sb[40];
    const int t = threadIdx.x;
    if (t < 40) sb[t] = bsum[t];
    __syncthreads();
    if (t == 0) {
        int acc = 0;
        for (int i = 0; i < 40; ++i) {
            int v = sb[i];
            sb[i] = acc;
            acc += v;
        }
        offs[NN] = EE;
    }
    __syncthreads();
    if (t < 40) bsum[t] = sb[t];
}

__global__ __launch_bounds__(256) void scan3(const int* __restrict__ cnt,
                                             const int* __restrict__ bsum,
                                             int* __restrict__ offs,
                                             int* __restrict__ cursor,
                                             float* __restrict__ dis) {
    const int idx = blockIdx.x * 256 + threadIdx.x;
    if (idx < NN) {
        int off = offs[idx] + bsum[blockIdx.x];
        offs[idx] = off;
        cursor[idx] = off;
        dis[idx] = rsqrtf((float)(cnt[idx] + 1));
    }
}

__global__ void fill_csr(const int* __restrict__ ei, int* __restrict__ cursor,
                         const float* __restrict__ dis, int* __restrict__ csr_src,
                         float* __restrict__ csr_norm) {
    int e = blockIdx.x * 256 + threadIdx.x;
    if (e < EE) {
        int s = ei[e];
        int d = ei[EE + e];
        int pos = atomicAdd(&cursor[d], 1);
        csr_src[pos] = s;
        csr_norm[pos] = dis[s] * dis[d];
    }
}

// ---------------- weight transpose+convert: Wt[col][k] bf16 ----------------
// blocks 0..255 -> Wt_zr (cols: 0-127 from Wz, 128-255 from Wr); 256..383 -> Wt_c.

__global__ __launch_bounds__(256) void wt_k(const float* __restrict__ Wz,
                                            const float* __restrict__ Wr,
                                            const float* __restrict__ Wc,
                                            ushort_t* __restrict__ Wt_zr,
                                            ushort_t* __restrict__ Wt_c) {
    const int col = blockIdx.x, k = threadIdx.x;
    if (col < 256) {
        float v = (col < 128) ? Wz[(size_t)k * 128 + col] : Wr[(size_t)k * 128 + col - 128];
        Wt_zr[(size_t)col * 256 + k] = f2b(v);
    } else {
        int c2 = col - 256;
        Wt_c[(size_t)c2 * 256 + k] = f2b(Wc[(size_t)k * 128 + c2]);
    }
}

// ---------------- GEMM: 128x128 tile, K=256 in 4 chunks of 64 ----------------
// A = [X | H] (f32, converted in staging) or [X | RH] (RH already bf16, SRC2=1).
// B = Wt[col][k] bf16 pre-transposed. Output bf16, T0/T1 picked by blockIdx.y.

template <int SRC2>
__global__ __launch_bounds__(256) void gemm_k(const float* __restrict__ X,
                                              const float* __restrict__ Hf,
                                              const ushort_t* __restrict__ RH,
                                              const ushort_t* __restrict__ Wt,
                                              ushort_t* __restrict__ T0,
                                              ushort_t* __restrict__ T1) {
    __shared__ __align__(16) ushort_t As[128 * 72];
    __shared__ __align__(16) ushort_t Bs[128 * 72];
    const int tid = threadIdx.x;
    const int rb0 = blockIdx.x * 128;
    const int cb0 = blockIdx.y * 128;
    ushort_t* T = (blockIdx.y == 0) ? T0 : T1;

    const int wv = tid >> 6, lane = tid & 63;
    const int l15 = lane & 15, q = lane >> 4;
    const int sr = tid >> 1;          // staging row (A) / col (B)
    const int kh = (tid & 1) * 32;    // staging k-half within chunk

    floatx4 acc[2][8];
#pragma unroll
    for (int i = 0; i < 2; ++i)
#pragma unroll
        for (int j = 0; j < 8; ++j) acc[i][j] = (floatx4){0.f, 0.f, 0.f, 0.f};

    for (int k0 = 0; k0 < 256; k0 += 64) {
        {  // A staging: 32 f32->bf16 (or bf16 copy) per thread
            const int kg = k0 + kh;
            ushort_t* dst = &As[sr * 72 + kh];
            if (kg < 128 || !SRC2) {
                const float* s = (kg < 128) ? (X + (size_t)(rb0 + sr) * DH + kg)
                                            : (Hf + (size_t)(rb0 + sr) * DH + (kg - 128));
#pragma unroll
                for (int i = 0; i < 4; ++i) {
                    float4 f0 = *(const float4*)(s + i * 8);
                    float4 f1 = *(const float4*)(s + i * 8 + 4);
                    ushort_t tmp[8] __attribute__((aligned(16)));
                    tmp[0] = f2b(f0.x); tmp[1] = f2b(f0.y);
                    tmp[2] = f2b(f0.z); tmp[3] = f2b(f0.w);
                    tmp[4] = f2b(f1.x); tmp[5] = f2b(f1.y);
                    tmp[6] = f2b(f1.z); tmp[7] = f2b(f1.w);
                    *(uint4*)(dst + i * 8) = *(const uint4*)tmp;
                }
            } else {
                const ushort_t* s = RH + (size_t)(rb0 + sr) * DH + (kg - 128);
#pragma unroll
                for (int i = 0; i < 4; ++i) *(uint4*)(dst + i * 8) = *(const uint4*)(s + i * 8);
            }
        }
        {  // B staging: coalesced bf16 copy
            const ushort_t* s = Wt + (size_t)(cb0 + sr) * 256 + k0 + kh;
            ushort_t* dst = &Bs[sr * 72 + kh];
#pragma unroll
            for (int i = 0; i < 4; ++i) *(uint4*)(dst + i * 8) = *(const uint4*)(s + i * 8);
        }
        __syncthreads();
#pragma unroll
        for (int ks = 0; ks < 2; ++ks) {
            const int ko = ks * 32 + q * 8;
            bf16x8 a0 = *(const bf16x8*)&As[(wv * 32 + l15) * 72 + ko];
            bf16x8 a1 = *(const bf16x8*)&As[(wv * 32 + 16 + l15) * 72 + ko];
#pragma unroll
            for (int j = 0; j < 8; ++j) {
                bf16x8 b = *(const bf16x8*)&Bs[(j * 16 + l15) * 72 + ko];
                acc[0][j] = __builtin_amdgcn_mfma_f32_16x16x32_bf16(a0, b, acc[0][j], 0, 0, 0);
                acc[1][j] = __builtin_amdgcn_mfma_f32_16x16x32_bf16(a1, b, acc[1][j], 0, 0, 0);
            }
        }
        __syncthreads();
    }

    // C/D layout: col = lane&15, row = (lane>>4)*4 + reg
#pragma unroll
    for (int i = 0; i < 2; ++i)
#pragma unroll
        for (int j = 0; j < 8; ++j)
#pragma unroll
            for (int v = 0; v < 4; ++v) {
                int row = rb0 + wv * 32 + i * 16 + q * 4 + v;
                T[(size_t)row * DH + j * 16 + l15] = f2b(acc[i][j][v]);
            }
}

// ---------------- gathers: one wave per (batch,node), 8-wide edge MLP ----------------
// batch = blockIdx&7 pins each batch's 2.56 MB slice to one XCD's L2.

#define EDGE_LOOP(BASE, A0, A1)                                            \
    for (; e + 8 <= e1; e += 8) {                                          \
        int ss[8];                                                         \
        float ww[8];                                                       \
        uint_t uu[8];                                                      \
        _Pragma("unroll") for (int i = 0; i < 8; ++i) ss[i] = csr_src[e + i]; \
        _Pragma("unroll") for (int i = 0; i < 8; ++i) ww[i] = csr_norm[e + i]; \
        _Pragma("unroll") for (int i = 0; i < 8; ++i)                      \
            uu[i] = *(const uint_t*)(BASE + (size_t)ss[i] * DH);           \
        _Pragma("unroll") for (int i = 0; i < 8; ++i) {                    \
            A0 += ww[i] * b2f(uu[i] & 0xffffu);                            \
            A1 += ww[i] * b2f(uu[i] >> 16);                                \
        }                                                                  \
    }                                                                      \
    for (; e < e1; ++e) {                                                  \
        int s_ = csr_src[e];                                               \
        float w_ = csr_norm[e];                                            \
        uint_t u_ = *(const uint_t*)(BASE + (size_t)s_ * DH);              \
        A0 += w_ * b2f(u_ & 0xffffu);                                      \
        A1 += w_ * b2f(u_ >> 16);                                          \
    }

__global__ __launch_bounds__(256) void gather_z(
    const ushort_t* __restrict__ tz, const int* __restrict__ offs,
    const int* __restrict__ csr_src, const float* __restrict__ csr_norm,
    const float* __restrict__ dis, const float* __restrict__ bz,
    ushort_t* __restrict__ z_buf) {
    const int tid = threadIdx.x, lane = tid & 63;
    const int b = blockIdx.x & 7;
    const int n = (blockIdx.x >> 3) * 4 + (tid >> 6);
    const size_t bo = (size_t)b * NN;
    const int c = lane * 2;
    const ushort_t* base = tz + bo * DH + c;

    float w0 = dis[n];
    w0 *= w0;
    uint_t u0 = *(const uint_t*)(base + (size_t)n * DH);
    float a0 = w0 * b2f(u0 & 0xffffu), a1 = w0 * b2f(u0 >> 16);

    int e = offs[n];
    const int e1 = offs[n + 1];
    EDGE_LOOP(base, a0, a1)

    float z0 = sigm(a0 + bz[c]), z1 = sigm(a1 + bz[c + 1]);
    *(uint_t*)(z_buf + (bo + n) * DH + c) = pack2(z0, z1);
}

__global__ __launch_bounds__(256) void gather_r(
    const ushort_t* __restrict__ tr, const float* __restrict__ h_prev,
    const int* __restrict__ offs, const int* __restrict__ csr_src,
    const float* __restrict__ csr_norm, const float* __restrict__ dis,
    const float* __restrict__ br, ushort_t* __restrict__ rh_buf) {
    const int tid = threadIdx.x, lane = tid & 63;
    const int b = blockIdx.x & 7;
    const int n = (blockIdx.x >> 3) * 4 + (tid >> 6);
    const size_t bo = (size_t)b * NN;
    const int c = lane * 2;
    const ushort_t* base = tr + bo * DH + c;

    float w0 = dis[n];
    w0 *= w0;
    uint_t u0 = *(const uint_t*)(base + (size_t)n * DH);
    float a0 = w0 * b2f(u0 & 0xffffu), a1 = w0 * b2f(u0 >> 16);

    int e = offs[n];
    const int e1 = offs[n + 1];
    EDGE_LOOP(base, a0, a1)

    float r0 = sigm(a0 + br[c]), r1 = sigm(a1 + br[c + 1]);
    float2 hv = *(const float2*)(h_prev + (bo + n) * DH + c);
    *(uint_t*)(rh_buf + (bo + n) * DH + c) = pack2(r0 * hv.x, r1 * hv.y);
}

__global__ __launch_bounds__(256) void gather_c(
    const ushort_t* __restrict__ tc, const float* __restrict__ h_prev,
    const int* __restrict__ offs, const int* __restrict__ csr_src,
    const float* __restrict__ csr_norm, const float* __restrict__ dis,
    const float* __restrict__ bcv, const ushort_t* __restrict__ z_buf,
    const float* __restrict__ gamma, const float* __restrict__ beta,
    float* __restrict__ out) {
    const int tid = threadIdx.x, lane = tid & 63;
    const int b = blockIdx.x & 7;
    const int n = (blockIdx.x >> 3) * 4 + (tid >> 6);
    const size_t bo = (size_t)b * NN;
    const int c = lane * 2;
    const ushort_t* base = tc + bo * DH + c;

    float w0 = dis[n];
    w0 *= w0;
    uint_t u0 = *(const uint_t*)(base + (size_t)n * DH);
    float a0 = w0 * b2f(u0 & 0xffffu), a1 = w0 * b2f(u0 >> 16);

    int e = offs[n];
    const int e1 = offs[n + 1];
    EDGE_LOOP(base, a0, a1)

    float hc0 = tanhf(a0 + bcv[c]);
    float hc1 = tanhf(a1 + bcv[c + 1]);
    uint_t zv = *(const uint_t*)(z_buf + (bo + n) * DH + c);
    float z0 = b2f(zv & 0xffffu), z1 = b2f(zv >> 16);
    float2 hv = *(const float2*)(h_prev + (bo + n) * DH + c);
    float hn0 = (1.0f - z0) * hv.x + z0 * hc0;
    float hn1 = (1.0f - z1) * hv.y + z1 * hc1;

    float s = hn0 + hn1;
#pragma unroll
    for (int o = 32; o > 0; o >>= 1) s += __shfl_xor(s, o);
    float mu = s * (1.0f / 128.0f);
    float d0 = hn0 - mu, d1 = hn1 - mu;
    float vv = d0 * d0 + d1 * d1;
#pragma unroll
    for (int o = 32; o > 0; o >>= 1) vv += __shfl_xor(vv, o);
    float inv = rsqrtf(vv * (1.0f / 128.0f) + LN_EPS);
    float2 ov;
    ov.x = d0 * inv * gamma[c] + beta[c];
    ov.y = d1 * inv * gamma[c + 1] + beta[c + 1];
    *(float2*)(out + (bo + n) * DH + c) = ov;
}

// ---------------- launch ----------------

extern "C" void kernel_launch(void* const* d_in, const int* in_sizes, int n_in,
                              void* d_out, int out_size, void* d_ws, size_t ws_size,
                              hipStream_t stream) {
    const float* x = (const float*)d_in[0];
    const int* ei = (const int*)d_in[1];
    const float* h = (const float*)d_in[2];
    const float* Wz = (const float*)d_in[3];
    const float* bz = (const float*)d_in[4];
    const float* Wr = (const float*)d_in[5];
    const float* br = (const float*)d_in[6];
    const float* Wc = (const float*)d_in[7];
    const float* bcv = (const float*)d_in[8];
    const float* gamma = (const float*)d_in[9];
    const float* beta = (const float*)d_in[10];
    float* out = (float*)d_out;

    char* w = (char*)d_ws;
    int* cnt = (int*)(w + 0);                   // 40000 B
    int* offs = (int*)(w + 40960);              // 40004 B
    int* cursor = (int*)(w + 81920);            // 40000 B
    float* dis = (float*)(w + 122880);          // 40000 B
    int* bsum = (int*)(w + 163840);             // 160 B
    ushort_t* Wt_zr = (ushort_t*)(w + 164864);  // 131072 B
    ushort_t* Wt_c = (ushort_t*)(w + 295936);   // 65536 B
    int* csr_src = (int*)(w + 362496);          // 640000 B
    float* csr_norm = (float*)(w + 1002496);    // 640000 B
    ushort_t* t_z = (ushort_t*)(w + 1644544);   // 20,480,000 B
    ushort_t* t_r = (ushort_t*)(w + 22124544);  // 20,480,000 B
    ushort_t* z_buf = (ushort_t*)(w + 42604544);// 20,480,000 B -> end 63,084,544
    ushort_t* rh_buf = t_z;  // t_z dead after gather_z
    ushort_t* t_c = t_r;     // t_r dead after gather_r

    hipMemsetAsync(cnt, 0, NN * sizeof(int), stream);
    count_deg<<<EE / 256, 256, 0, stream>>>(ei, cnt);
    scan1<<<40, 256, 0, stream>>>(cnt, offs, bsum);
    scan2<<<1, 64, 0, stream>>>(bsum, offs);
    scan3<<<40, 256, 0, stream>>>(cnt, bsum, offs, cursor, dis);
    fill_csr<<<EE / 256, 256, 0, stream>>>(ei, cursor, dis, csr_src, csr_norm);
    wt_k<<<384, 256, 0, stream>>>(Wz, Wr, Wc, Wt_zr, Wt_c);

    // t_z|t_r = [x|h] @ [Wz|Wr]  (80000 x 128 each)
    gemm_k<0><<<dim3(80000 / 128, 2), 256, 0, stream>>>(x, h, (const ushort_t*)0, Wt_zr,
                                                        t_z, t_r);
    gather_z<<<(BB * NN) / 4, 256, 0, stream>>>(t_z, offs, csr_src, csr_norm, dis, bz, z_buf);
    gather_r<<<(BB * NN) / 4, 256, 0, stream>>>(t_r, h, offs, csr_src, csr_norm, dis, br,
                                                rh_buf);
    // t_c = [x|r*h] @ Wc  (80000 x 128)
    gemm_k<1><<<dim3(80000 / 128, 1), 256, 0, stream>>>(x, (const float*)0, rh_buf, Wt_c,
                                                        t_c, t_c);
    gather_c<<<(BB * NN) / 4, 256, 0, stream>>>(t_c, h, offs, csr_src, csr_norm, dis, bcv,
                                                z_buf, gamma, beta, out);
}